// Round 3
// baseline (10892.193 us; speedup 1.0000x reference)
//
#include <hip/hip_runtime.h>

// ============================================================================
// 2-layer LSTM (B=64,T=512,I=256,H=1024) + head. Persistent kernel, R8.
//
// R8 vs R7 (4564us, 8.9us/step, 84% idle => publish drain + B-load stalls
// still in the period):
//  * PRODUCER-WAVE SPECIALIZATION: wave 0 does NO GEMM. Per step it only
//    runs {barrier1 -> pointwise share -> barrier2 -> slot-gate + pack +
//    vstore16 + vmcnt(0) drain + flag}. The MALL write-ack drain now fully
//    overlaps waves 1-7's next-step GEMM instead of lagging barrier1.
//  * Waves 1-7 cover the K-chunks: L0 {6,6,6,6,6,5,5}=40; L1 per phase
//    {5,5,5,5,4,4,4}=32. gbufT shrinks to [7][128][24] = 86,016 B.
//  * FULL-PHASE B PREFETCH: each wave issues ALL its phase's weight frags
//    (<=6 chunks x 8 = <=96 VGPR) BEFORE the flag spin -> the L2 weight
//    stream flows during spin + A-RTT; no per-chunk 200cy exposed stalls.
//  * Spin sleep 2 -> 1 (faster detect; flag lines few + read-shared).
//  * Keep from R7: per-wave point-of-use spins; phase A (h0) before
//    phase B (h2 recurrent chain); 1-line-per-group flags; publish =
//    vstore16 -> vmcnt(0) -> flag store; full-depth A prefetch.
//
// Workspace (44,834,816 B):
//   0         W0p  fp16 [32 cs][40 c][8 nt][512]   10,485,760
//   10485760  W1p  fp16 [32 cs][64 c][8 nt][512]   16,777,216
//   27262976  h0q  fp16 4 slots x [32 c][4 bg][512]   524,288
//   27787264  h2q  fp16 2 slots x same                262,144
//   28049408  sync uint[2048]: flag[(lay*4+bg)*32 + cs], 128B/group  8,192
//   28057600  xpk  fp16 [512 t][8 c][4 bg][512]    16,777,216
// ============================================================================

typedef _Float16 h8 __attribute__((ext_vector_type(8)));
typedef float    f4 __attribute__((ext_vector_type(4)));
typedef unsigned long long u64;

#define WS_W0P   0
#define WS_W1P   10485760
#define WS_H0Q   27262976
#define WS_H2Q   27787264
#define WS_SYNC  28049408
#define WS_XPK   28057600
#define WS_XPK_END 44834816ULL

static __device__ __forceinline__ float sigm(float v) { return 1.f / (1.f + __expf(-v)); }
static __device__ __forceinline__ float tanh_fast(float v) {
  const float e = __expf(2.f * v);
  return 1.f - 2.f / (e + 1.f);
}
static __device__ __forceinline__ h8 vload16(const _Float16* p) {
  return *(const volatile h8*)p;          // coherent (MALL) 16B load
}
static __device__ __forceinline__ void vstore16(_Float16* p, h8 v) {
  *(volatile h8*)p = v;                   // coherent (MALL) 16B store
}

// ---------------------------------------------------------------------------
__global__ void prep_kernel(const float* __restrict__ x,
                            const float* __restrict__ Wih0, const float* __restrict__ Whh0,
                            const float* __restrict__ Wih1, const float* __restrict__ Whh1,
                            _Float16* __restrict__ W0p, _Float16* __restrict__ W1p,
                            _Float16* __restrict__ xpk,
                            unsigned* __restrict__ hz, unsigned* __restrict__ sync_ws)
{
  const long tid0 = (long)blockIdx.x * blockDim.x + threadIdx.x;
  const long np   = (long)gridDim.x * blockDim.x;

  // W0p: e = ((cs*40 + c)*8 + nt)*512 + l15*32 + quad*8 + j
  for (long e = tid0; e < 5242880; e += np) {
    const int j = e & 7, quad = (e >> 3) & 3, l15 = (e >> 5) & 15, nt = (e >> 9) & 7;
    const int r = (int)(e >> 12);
    const int c = r % 40, cs = r / 40;
    const int col = nt * 16 + l15;
    const int row = (col >> 5) * 1024 + cs * 32 + (col & 31);
    const int k = c * 32 + quad * 8 + j;
    const float v = (k < 256) ? Wih0[(long)row * 256 + k] : Whh0[(long)row * 1024 + k - 256];
    W0p[e] = (_Float16)v;
  }
  // W1p: r = cs*64 + c
  for (long e = tid0; e < 8388608; e += np) {
    const int j = e & 7, quad = (e >> 3) & 3, l15 = (e >> 5) & 15, nt = (e >> 9) & 7;
    const int r = (int)(e >> 12);
    const int c = r & 63, cs = r >> 6;
    const int col = nt * 16 + l15;
    const int row = (col >> 5) * 1024 + cs * 32 + (col & 31);
    const int k = c * 32 + quad * 8 + j;
    const float v = (k < 1024) ? Wih1[(long)row * 1024 + k] : Whh1[(long)row * 1024 + k - 1024];
    W1p[e] = (_Float16)v;
  }
  // xpk: e = ((t*8 + c)*4 + bg)*512 + b16*32 + k32
  if (xpk) {
    for (long e = tid0; e < 8388608; e += np) {
      const int k32 = e & 31, b16 = (e >> 5) & 15, bg = (e >> 9) & 3;
      const int c = (e >> 11) & 7;
      const int t = (int)(e >> 14);
      const int b = bg * 16 + b16, k = c * 32 + k32;
      xpk[e] = (_Float16)x[(long)b * 131072 + (long)t * 256 + k];
    }
  }
  for (long e = tid0; e < 196608; e += np) hz[e] = 0u;   // h0q + h2q
  if (tid0 < 2048) sync_ws[tid0] = 0u;
}

// ---------------------------------------------------------------------------
// sync layout (uint idx): flag[(lay*4+bg)*32 + cs]. One 128-B line per
// (lay,bg) group. Flag value = n+1 once that WG's h(n) slice is MALL-visible.
// ---------------------------------------------------------------------------
template<bool XP>
__launch_bounds__(512, 1)
__global__ void lstm_kernel(const float* __restrict__ x, const _Float16* __restrict__ xpk,
                            const float* __restrict__ bih0, const float* __restrict__ bhh0,
                            const float* __restrict__ bih1, const float* __restrict__ bhh1,
                            const _Float16* __restrict__ W0p, const _Float16* __restrict__ W1p,
                            _Float16* __restrict__ h0q, _Float16* __restrict__ h2q,
                            unsigned* __restrict__ sy)
{
  extern __shared__ float gb[];                    // gbufT [7][128][24] = 86,016 B
  __shared__ float cst[512];                       // c-state, slot = tid (hh*16+b16)
  __shared__ float biasl[128];
  __shared__ _Float16 htmp[32 * 18];               // [hh][b16] pad 18

  const int tid = threadIdx.x, wg = blockIdx.x;
  const int xcd = wg & 7, jdec = wg >> 3;
  const int lay = jdec & 1, jj = jdec >> 1;
  const int bg = jj & 3, csl = jj >> 2;
  const int cs = xcd * 4 + csl;                    // col-slice 0..31 (XCD-local)
  const int lane = tid & 63, kg = tid >> 6;        // kg 0 = publisher wave
  const int l15 = lane & 15, quad = lane >> 4;
  const int boff = l15 * 32 + quad * 8;            // B-frag offset in 1024-blk
  const int aoff = bg * 512 + l15 * 32 + quad * 8; // A-frag offset in 2048-blk

  const _Float16* Wp = lay ? (W1p + (long)cs * 262144) : (W0p + (long)cs * 163840);

  if (tid < 128) {
    const int row = (tid >> 5) * 1024 + cs * 32 + (tid & 31);
    biasl[tid] = lay ? (bih1[row] + bhh1[row]) : (bih0[row] + bhh0[row]);
  }
  cst[tid] = 0.f;
  __syncthreads();

  unsigned* const fL0  = sy + (bg * 32);           // layer-0 flags, this bg (1 line)
  unsigned* const fL1  = sy + ((4 + bg) * 32);     // layer-1 flags, this bg (1 line)
  unsigned* const fOwn = (lay ? fL1 : fL0) + cs;   // this WG's flag

  auto spin1 = [&](const unsigned* p, int tgt) {   // exits immediately if tgt<=0
    while ((int)__hip_atomic_load(p, __ATOMIC_RELAXED, __HIP_MEMORY_SCOPE_AGENT) < tgt)
      __builtin_amdgcn_s_sleep(1);
  };

  auto dump = [&](const f4* acc) {                 // kg>=1 only
#pragma unroll
    for (int nt = 0; nt < 8; ++nt)
      *(f4*)&gb[((kg - 1) * 128 + nt * 16 + l15) * 24 + quad * 4] = acc[nt];
  };

  // gate: slot-free flags (fL1), gtgt: required value; polled by wave-0 lanes
  auto pointwise_publish = [&](_Float16* wr, int n, int gtgt) {
    __syncthreads();                               // gbufT complete
    {
      const int b16 = tid & 15, hh = tid >> 4;
      float gv[4];
#pragma unroll
      for (int gt = 0; gt < 4; ++gt) {
        float s = biasl[gt * 32 + hh];
#pragma unroll
        for (int k = 0; k < 7; ++k) s += gb[(k * 128 + gt * 32 + hh) * 24 + b16];
        gv[gt] = s;
      }
      const float si = sigm(gv[0]), sf = sigm(gv[1]);
      const float tg = tanh_fast(gv[2]), so = sigm(gv[3]);
      const float cn = sf * cst[tid] + si * tg;
      cst[tid] = cn;
      htmp[hh * 18 + b16] = (_Float16)(so * tanh_fast(cn));
    }
    __syncthreads();                               // htmp complete; waves 1-7 run ahead
    if (tid < 64) {                                // wave 0: gate + pack + publish + flag
      if (tid < 32) spin1(fL1 + tid, gtgt);        // slot-free (usually satisfied)
      const int b16 = tid & 15, q = tid >> 4;
      union { h8 v; _Float16 e[8]; } r;
#pragma unroll
      for (int i = 0; i < 8; ++i) r.e[i] = htmp[(q * 8 + i) * 18 + b16];
      vstore16(wr + (cs * 4 + bg) * 512 + b16 * 32 + q * 8, r.v);
      asm volatile("s_waitcnt vmcnt(0)" ::: "memory");   // wave-local drain
      if (tid == 0)
        __hip_atomic_store(fOwn, (unsigned)(n + 1),
                           __ATOMIC_RELAXED, __HIP_MEMORY_SCOPE_AGENT);
    }
  };

  if (lay == 0) {
    // waves 1..7 cover 40 chunks: {6,6,6,6,6,5,5}
    const int c0 = (kg <= 6) ? (kg - 1) * 6 : 35;
    const int nc = (kg <= 5) ? 6 : 5;
    for (int n = 0; n < 512; ++n) {
      if (kg >= 1) {
        const _Float16* h0prev = h0q + ((n - 1) & 3) * 65536;
        const _Float16* xs = XP ? (xpk + (long)n * 16384) : nullptr;

        f4 acc[8] = {};
        h8 Ab[6]; h8 Bb[6][8];
        auto loadB = [&](int c, int sl) {
          const _Float16* bp = Wp + (long)c * 4096 + boff;
#pragma unroll
          for (int nt = 0; nt < 8; ++nt) Bb[sl][nt] = *(const h8*)(bp + nt * 512);
        };
        auto loadA = [&](int c, int idx) {
          if (c < 8) {
            if (XP) Ab[idx] = *(const h8*)(xs + c * 2048 + aoff);
            else {
              const float* q = x + (long)(bg * 16 + l15) * 131072 + (long)n * 256 + c * 32 + quad * 8;
              const f4 v0 = *(const f4*)q;
              const f4 v1 = *(const f4*)(q + 4);
              h8 t;
              t[0]=(_Float16)v0[0]; t[1]=(_Float16)v0[1]; t[2]=(_Float16)v0[2]; t[3]=(_Float16)v0[3];
              t[4]=(_Float16)v1[0]; t[5]=(_Float16)v1[1]; t[6]=(_Float16)v1[2]; t[7]=(_Float16)v1[3];
              Ab[idx] = t;
            }
          } else {
            Ab[idx] = vload16(h0prev + (c - 8) * 2048 + aoff);
          }
        };

        // full-phase B prefetch + independent x-chunks, all pre-spin
#pragma unroll
        for (int i = 0; i < 6; ++i) if (i < nc) loadB(c0 + i, i);
#pragma unroll
        for (int i = 0; i < 6; ++i) if (i < nc && (c0 + i) < 8) loadA(c0 + i, i);

        // per-wave point-of-use spin (lanes poll this wave's producers only)
        if (lane < nc) {
          const int c = c0 + lane;
          if (c >= 8) spin1(fL0 + (c - 8), n);     // h0(n-1) slice visible
        }

#pragma unroll
        for (int i = 0; i < 6; ++i) if (i < nc && (c0 + i) >= 8) loadA(c0 + i, i);

#pragma unroll
        for (int i = 0; i < 6; ++i) if (i < nc) {
          const h8 A = Ab[i];
#pragma unroll
          for (int nt = 0; nt < 8; ++nt)
            acc[nt] = __builtin_amdgcn_mfma_f32_16x16x32_f16(A, Bb[i][nt], acc[nt], 0, 0, 0);
        }
        dump(acc);
      }
      // slot n&3 overwrites h0(n-4): L1 consumers (step n-4) done iff fL1 >= n-3.
      pointwise_publish(h0q + (n & 3) * 65536, n, n - 3);
    }
  } else {
    // waves 1..7 cover 32 chunks per phase: {5,5,5,5,4,4,4}
    const int c0 = (kg <= 5) ? (kg - 1) * 5 : 20 + (kg - 5) * 4;
    const int nc = (kg <= 4) ? 5 : 4;
    for (int n = 0; n < 512; ++n) {
      if (kg >= 1) {
        const _Float16* h0cur  = h0q + (n & 3) * 65536;
        const _Float16* h2prev = h2q + ((n - 1) & 1) * 65536;

        f4 acc[8] = {};
        h8 Ab[5]; h8 Bb[5][8];
        auto loadB = [&](int c, int sl) {
          const _Float16* bp = Wp + (long)c * 4096 + boff;
#pragma unroll
          for (int nt = 0; nt < 8; ++nt) Bb[sl][nt] = *(const h8*)(bp + nt * 512);
        };
        auto loadA = [&](const _Float16* hb, int cloc, int idx) {
          Ab[idx] = vload16(hb + cloc * 2048 + aoff);
        };

        // ---- phase A: h0(n) part (weights c0..) — L0 runs ahead, usually
        // ready; hides the h2 recurrent-chain spin behind this GEMM.
#pragma unroll
        for (int i = 0; i < 5; ++i) if (i < nc) loadB(c0 + i, i);   // full prefetch
        if (lane < nc) spin1(fL0 + c0 + lane, n + 1);               // h0(n) visible
#pragma unroll
        for (int i = 0; i < 5; ++i) if (i < nc) loadA(h0cur, c0 + i, i);
#pragma unroll
        for (int i = 0; i < 5; ++i) if (i < nc) {
          const h8 A = Ab[i];
#pragma unroll
          for (int nt = 0; nt < 8; ++nt)
            acc[nt] = __builtin_amdgcn_mfma_f32_16x16x32_f16(A, Bb[i][nt], acc[nt], 0, 0, 0);
        }

        // ---- phase B: h2(n-1) part (weights 32+c0..) — the recurrent chain
#pragma unroll
        for (int i = 0; i < 5; ++i) if (i < nc) loadB(32 + c0 + i, i);
        if (lane < nc) spin1(fL1 + c0 + lane, n);                   // h2(n-1) visible
#pragma unroll
        for (int i = 0; i < 5; ++i) if (i < nc) loadA(h2prev, c0 + i, i);
#pragma unroll
        for (int i = 0; i < 5; ++i) if (i < nc) {
          const h8 A = Ab[i];
#pragma unroll
          for (int nt = 0; nt < 8; ++nt)
            acc[nt] = __builtin_amdgcn_mfma_f32_16x16x32_f16(A, Bb[i][nt], acc[nt], 0, 0, 0);
        }
        dump(acc);
      }
      // slot n&1 overwrites h2(n-2): L1 peers (step n-1 phase B) done iff fL1 >= n.
      pointwise_publish(h2q + (n & 1) * 65536, n, n);
    }
  }
}

// ---------------------------------------------------------------------------
__global__ void head_kernel(const _Float16* __restrict__ h2s, const float* __restrict__ Wh,
                            const float* __restrict__ bh, float* __restrict__ out)
{
  const int blk = blockIdx.x;            // 64*24
  const int b = blk / 24, j = blk % 24;
  const int lane = threadIdx.x;          // 64
  float sum = 0.f;
#pragma unroll
  for (int k0 = 0; k0 < 1024; k0 += 64) {
    const int hid = k0 + lane;
    const float hv = (float)h2s[((hid >> 5) * 4 + (b >> 4)) * 512 + (b & 15) * 32 + (hid & 31)];
    sum += hv * Wh[(long)j * 1024 + hid];
  }
#pragma unroll
  for (int off = 32; off > 0; off >>= 1)
    sum += __shfl_down(sum, off, 64);
  if (lane == 0) out[b * 24 + j] = sum + bh[j];
}

// ---------------------------------------------------------------------------
extern "C" void kernel_launch(void* const* d_in, const int* in_sizes, int n_in,
                              void* d_out, int out_size, void* d_ws, size_t ws_size,
                              hipStream_t stream)
{
  const float* x    = (const float*)d_in[0];
  const float* Wih0 = (const float*)d_in[1];
  const float* Whh0 = (const float*)d_in[2];
  const float* bih0 = (const float*)d_in[3];
  const float* bhh0 = (const float*)d_in[4];
  const float* Wih1 = (const float*)d_in[5];
  const float* Whh1 = (const float*)d_in[6];
  const float* bih1 = (const float*)d_in[7];
  const float* bhh1 = (const float*)d_in[8];
  const float* Whd  = (const float*)d_in[9];
  const float* bhd  = (const float*)d_in[10];

  char* ws = (char*)d_ws;
  _Float16* W0p     = (_Float16*)(ws + WS_W0P);
  _Float16* W1p     = (_Float16*)(ws + WS_W1P);
  _Float16* h0q     = (_Float16*)(ws + WS_H0Q);
  _Float16* h2q     = (_Float16*)(ws + WS_H2Q);
  unsigned* sync_ws = (unsigned*)(ws + WS_SYNC);
  float* out = (float*)d_out;

  const bool use_xpk = (ws_size >= WS_XPK_END);
  _Float16* xpk = use_xpk ? (_Float16*)(ws + WS_XPK) : nullptr;

  prep_kernel<<<dim3(2048), dim3(256), 0, stream>>>(
      x, Wih0, Whh0, Wih1, Whh1, W0p, W1p, xpk,
      (unsigned*)(ws + WS_H0Q), sync_ws);

  // static ~3.7 KB + dynamic 86,016 B LDS -> 1 WG/CU -> 256 WGs co-resident.
  if (use_xpk)
    lstm_kernel<true><<<dim3(256), dim3(512), 86016, stream>>>(
        x, xpk, bih0, bhh0, bih1, bhh1, W0p, W1p, h0q, h2q, sync_ws);
  else
    lstm_kernel<false><<<dim3(256), dim3(512), 86016, stream>>>(
        x, nullptr, bih0, bhh0, bih1, bhh1, W0p, W1p, h0q, h2q, sync_ws);

  head_kernel<<<dim3(64 * 24), dim3(64), 0, stream>>>(
      h2q + 65536, Whd, bhd, out);   // h2(511), slot 511&1 = 1
}

// Round 4
// 7510.321 us; speedup vs baseline: 1.4503x; 1.4503x over previous
//
#include <hip/hip_runtime.h>

// ============================================================================
// 2-layer LSTM (B=64,T=512,I=256,H=1024) + head. Persistent kernel, R9.
//
// R9 vs R8 (10892us — REGRESSION was a VGPR spill: Bb[6][8] = 192 VGPRs for
// weights alone pushed past the 256/wave cap -> scratch -> 17.6 GB HBM):
//  * 3-DEEP MODULO B PIPELINE, not full-phase: Bb[3][8] = 96 VGPR. Prologue
//    issues 3 chunks pre-spin; loop does MFMA(chunk i, slot i%3) then issues
//    chunk i+3 into the freed slot. ~2-3 chunks of weight loads in flight,
//    ~80-120cy MFMA cover each, 2nd compute wave on the SIMD hides the rest.
//    Total ~150-190 VGPR -> no spill (verify: VGPR_Count < 256, FETCH back
//    to ~6.2e5 KB).
//  * KEEP producer-wave specialization (untested in R8, masked by spill):
//    wave 0 does no GEMM; publish drain overlaps waves 1-7's next phase.
//    Waves 1-7 cover chunks: L0 {6,6,6,6,6,5,5}=40; L1/phase {5,5,5,5,4,4,4}.
//  * KEEP from R7: per-wave point-of-use spins; phase A (h0, usually ready)
//    before phase B (h2 recurrent chain); 1-line-per-group flags; publish =
//    vstore16 -> vmcnt(0) -> flag store; gbufT [7][128][24].
//
// Workspace (44,834,816 B):
//   0         W0p  fp16 [32 cs][40 c][8 nt][512]   10,485,760
//   10485760  W1p  fp16 [32 cs][64 c][8 nt][512]   16,777,216
//   27262976  h0q  fp16 4 slots x [32 c][4 bg][512]   524,288
//   27787264  h2q  fp16 2 slots x same                262,144
//   28049408  sync uint[2048]: flag[(lay*4+bg)*32 + cs], 128B/group  8,192
//   28057600  xpk  fp16 [512 t][8 c][4 bg][512]    16,777,216
// ============================================================================

typedef _Float16 h8 __attribute__((ext_vector_type(8)));
typedef float    f4 __attribute__((ext_vector_type(4)));
typedef unsigned long long u64;

#define WS_W0P   0
#define WS_W1P   10485760
#define WS_H0Q   27262976
#define WS_H2Q   27787264
#define WS_SYNC  28049408
#define WS_XPK   28057600
#define WS_XPK_END 44834816ULL

static __device__ __forceinline__ float sigm(float v) { return 1.f / (1.f + __expf(-v)); }
static __device__ __forceinline__ float tanh_fast(float v) {
  const float e = __expf(2.f * v);
  return 1.f - 2.f / (e + 1.f);
}
static __device__ __forceinline__ h8 vload16(const _Float16* p) {
  return *(const volatile h8*)p;          // coherent (MALL) 16B load
}
static __device__ __forceinline__ void vstore16(_Float16* p, h8 v) {
  *(volatile h8*)p = v;                   // coherent (MALL) 16B store
}

// ---------------------------------------------------------------------------
__global__ void prep_kernel(const float* __restrict__ x,
                            const float* __restrict__ Wih0, const float* __restrict__ Whh0,
                            const float* __restrict__ Wih1, const float* __restrict__ Whh1,
                            _Float16* __restrict__ W0p, _Float16* __restrict__ W1p,
                            _Float16* __restrict__ xpk,
                            unsigned* __restrict__ hz, unsigned* __restrict__ sync_ws)
{
  const long tid0 = (long)blockIdx.x * blockDim.x + threadIdx.x;
  const long np   = (long)gridDim.x * blockDim.x;

  // W0p: e = ((cs*40 + c)*8 + nt)*512 + l15*32 + quad*8 + j
  for (long e = tid0; e < 5242880; e += np) {
    const int j = e & 7, quad = (e >> 3) & 3, l15 = (e >> 5) & 15, nt = (e >> 9) & 7;
    const int r = (int)(e >> 12);
    const int c = r % 40, cs = r / 40;
    const int col = nt * 16 + l15;
    const int row = (col >> 5) * 1024 + cs * 32 + (col & 31);
    const int k = c * 32 + quad * 8 + j;
    const float v = (k < 256) ? Wih0[(long)row * 256 + k] : Whh0[(long)row * 1024 + k - 256];
    W0p[e] = (_Float16)v;
  }
  // W1p: r = cs*64 + c
  for (long e = tid0; e < 8388608; e += np) {
    const int j = e & 7, quad = (e >> 3) & 3, l15 = (e >> 5) & 15, nt = (e >> 9) & 7;
    const int r = (int)(e >> 12);
    const int c = r & 63, cs = r >> 6;
    const int col = nt * 16 + l15;
    const int row = (col >> 5) * 1024 + cs * 32 + (col & 31);
    const int k = c * 32 + quad * 8 + j;
    const float v = (k < 1024) ? Wih1[(long)row * 1024 + k] : Whh1[(long)row * 1024 + k - 1024];
    W1p[e] = (_Float16)v;
  }
  // xpk: e = ((t*8 + c)*4 + bg)*512 + b16*32 + k32
  if (xpk) {
    for (long e = tid0; e < 8388608; e += np) {
      const int k32 = e & 31, b16 = (e >> 5) & 15, bg = (e >> 9) & 3;
      const int c = (e >> 11) & 7;
      const int t = (int)(e >> 14);
      const int b = bg * 16 + b16, k = c * 32 + k32;
      xpk[e] = (_Float16)x[(long)b * 131072 + (long)t * 256 + k];
    }
  }
  for (long e = tid0; e < 196608; e += np) hz[e] = 0u;   // h0q + h2q
  if (tid0 < 2048) sync_ws[tid0] = 0u;
}

// ---------------------------------------------------------------------------
// sync layout (uint idx): flag[(lay*4+bg)*32 + cs]. One 128-B line per
// (lay,bg) group. Flag value = n+1 once that WG's h(n) slice is MALL-visible.
// ---------------------------------------------------------------------------
template<bool XP>
__launch_bounds__(512, 1)
__global__ void lstm_kernel(const float* __restrict__ x, const _Float16* __restrict__ xpk,
                            const float* __restrict__ bih0, const float* __restrict__ bhh0,
                            const float* __restrict__ bih1, const float* __restrict__ bhh1,
                            const _Float16* __restrict__ W0p, const _Float16* __restrict__ W1p,
                            _Float16* __restrict__ h0q, _Float16* __restrict__ h2q,
                            unsigned* __restrict__ sy)
{
  extern __shared__ float gb[];                    // gbufT [7][128][24] = 86,016 B
  __shared__ float cst[512];                       // c-state, slot = tid (hh*16+b16)
  __shared__ float biasl[128];
  __shared__ _Float16 htmp[32 * 18];               // [hh][b16] pad 18

  const int tid = threadIdx.x, wg = blockIdx.x;
  const int xcd = wg & 7, jdec = wg >> 3;
  const int lay = jdec & 1, jj = jdec >> 1;
  const int bg = jj & 3, csl = jj >> 2;
  const int cs = xcd * 4 + csl;                    // col-slice 0..31 (XCD-local)
  const int lane = tid & 63, kg = tid >> 6;        // kg 0 = publisher wave
  const int l15 = lane & 15, quad = lane >> 4;
  const int boff = l15 * 32 + quad * 8;            // B-frag offset in 1024-blk
  const int aoff = bg * 512 + l15 * 32 + quad * 8; // A-frag offset in 2048-blk

  const _Float16* Wp = lay ? (W1p + (long)cs * 262144) : (W0p + (long)cs * 163840);

  if (tid < 128) {
    const int row = (tid >> 5) * 1024 + cs * 32 + (tid & 31);
    biasl[tid] = lay ? (bih1[row] + bhh1[row]) : (bih0[row] + bhh0[row]);
  }
  cst[tid] = 0.f;
  __syncthreads();

  unsigned* const fL0  = sy + (bg * 32);           // layer-0 flags, this bg (1 line)
  unsigned* const fL1  = sy + ((4 + bg) * 32);     // layer-1 flags, this bg (1 line)
  unsigned* const fOwn = (lay ? fL1 : fL0) + cs;   // this WG's flag

  auto spin1 = [&](const unsigned* p, int tgt) {   // exits immediately if tgt<=0
    while ((int)__hip_atomic_load(p, __ATOMIC_RELAXED, __HIP_MEMORY_SCOPE_AGENT) < tgt)
      __builtin_amdgcn_s_sleep(1);
  };

  auto dump = [&](const f4* acc) {                 // kg>=1 only
#pragma unroll
    for (int nt = 0; nt < 8; ++nt)
      *(f4*)&gb[((kg - 1) * 128 + nt * 16 + l15) * 24 + quad * 4] = acc[nt];
  };

  // gate: slot-free flags (fL1), gtgt: required value; polled by wave-0 lanes
  auto pointwise_publish = [&](_Float16* wr, int n, int gtgt) {
    __syncthreads();                               // gbufT complete
    {
      const int b16 = tid & 15, hh = tid >> 4;
      float gv[4];
#pragma unroll
      for (int gt = 0; gt < 4; ++gt) {
        float s = biasl[gt * 32 + hh];
#pragma unroll
        for (int k = 0; k < 7; ++k) s += gb[(k * 128 + gt * 32 + hh) * 24 + b16];
        gv[gt] = s;
      }
      const float si = sigm(gv[0]), sf = sigm(gv[1]);
      const float tg = tanh_fast(gv[2]), so = sigm(gv[3]);
      const float cn = sf * cst[tid] + si * tg;
      cst[tid] = cn;
      htmp[hh * 18 + b16] = (_Float16)(so * tanh_fast(cn));
    }
    __syncthreads();                               // htmp complete; waves 1-7 run ahead
    if (tid < 64) {                                // wave 0: gate + pack + publish + flag
      if (tid < 32) spin1(fL1 + tid, gtgt);        // slot-free (usually satisfied)
      const int b16 = tid & 15, q = tid >> 4;
      union { h8 v; _Float16 e[8]; } r;
#pragma unroll
      for (int i = 0; i < 8; ++i) r.e[i] = htmp[(q * 8 + i) * 18 + b16];
      vstore16(wr + (cs * 4 + bg) * 512 + b16 * 32 + q * 8, r.v);
      asm volatile("s_waitcnt vmcnt(0)" ::: "memory");   // wave-local drain
      if (tid == 0)
        __hip_atomic_store(fOwn, (unsigned)(n + 1),
                           __ATOMIC_RELAXED, __HIP_MEMORY_SCOPE_AGENT);
    }
  };

  if (lay == 0) {
    // waves 1..7 cover 40 chunks: {6,6,6,6,6,5,5}
    const int c0 = (kg <= 6) ? (kg - 1) * 6 : 35;
    const int nc = (kg <= 5) ? 6 : 5;
    for (int n = 0; n < 512; ++n) {
      if (kg >= 1) {
        const _Float16* h0prev = h0q + ((n - 1) & 3) * 65536;
        const _Float16* xs = XP ? (xpk + (long)n * 16384) : nullptr;

        f4 acc[8] = {};
        h8 Ab[6]; h8 Bb[3][8];
        auto loadB = [&](int c, int sl) {
          const _Float16* bp = Wp + (long)c * 4096 + boff;
#pragma unroll
          for (int nt = 0; nt < 8; ++nt) Bb[sl][nt] = *(const h8*)(bp + nt * 512);
        };
        auto loadA = [&](int c, int idx) {
          if (c < 8) {
            if (XP) Ab[idx] = *(const h8*)(xs + c * 2048 + aoff);
            else {
              const float* q = x + (long)(bg * 16 + l15) * 131072 + (long)n * 256 + c * 32 + quad * 8;
              const f4 v0 = *(const f4*)q;
              const f4 v1 = *(const f4*)(q + 4);
              h8 t;
              t[0]=(_Float16)v0[0]; t[1]=(_Float16)v0[1]; t[2]=(_Float16)v0[2]; t[3]=(_Float16)v0[3];
              t[4]=(_Float16)v1[0]; t[5]=(_Float16)v1[1]; t[6]=(_Float16)v1[2]; t[7]=(_Float16)v1[3];
              Ab[idx] = t;
            }
          } else {
            Ab[idx] = vload16(h0prev + (c - 8) * 2048 + aoff);
          }
        };

        // 3-deep B prologue + independent x-chunks, all pre-spin
        loadB(c0, 0);
        loadB(c0 + 1, 1);
        loadB(c0 + 2, 2);
#pragma unroll
        for (int i = 0; i < 6; ++i) if (i < nc && (c0 + i) < 8) loadA(c0 + i, i);

        // per-wave point-of-use spin (lanes poll this wave's producers only)
        if (lane < nc) {
          const int c = c0 + lane;
          if (c >= 8) spin1(fL0 + (c - 8), n);     // h0(n-1) slice visible
        }

#pragma unroll
        for (int i = 0; i < 6; ++i) if (i < nc && (c0 + i) >= 8) loadA(c0 + i, i);

#pragma unroll
        for (int i = 0; i < 6; ++i) if (i < nc) {
          const h8 A = Ab[i];
#pragma unroll
          for (int nt = 0; nt < 8; ++nt)
            acc[nt] = __builtin_amdgcn_mfma_f32_16x16x32_f16(A, Bb[i % 3][nt], acc[nt], 0, 0, 0);
          if (i + 3 < nc) loadB(c0 + i + 3, i % 3);   // refill freed slot
        }
        dump(acc);
      }
      // slot n&3 overwrites h0(n-4): L1 consumers (step n-4) done iff fL1 >= n-3.
      pointwise_publish(h0q + (n & 3) * 65536, n, n - 3);
    }
  } else {
    // waves 1..7 cover 32 chunks per phase: {5,5,5,5,4,4,4}
    const int c0 = (kg <= 5) ? (kg - 1) * 5 : 20 + (kg - 5) * 4;
    const int nc = (kg <= 4) ? 5 : 4;
    for (int n = 0; n < 512; ++n) {
      if (kg >= 1) {
        const _Float16* h0cur  = h0q + (n & 3) * 65536;
        const _Float16* h2prev = h2q + ((n - 1) & 1) * 65536;

        f4 acc[8] = {};
        h8 Ab[5]; h8 Bb[3][8];
        auto loadB = [&](int c, int sl) {
          const _Float16* bp = Wp + (long)c * 4096 + boff;
#pragma unroll
          for (int nt = 0; nt < 8; ++nt) Bb[sl][nt] = *(const h8*)(bp + nt * 512);
        };
        auto loadA = [&](const _Float16* hb, int cloc, int idx) {
          Ab[idx] = vload16(hb + cloc * 2048 + aoff);
        };

        // ---- phase A: h0(n) part (weights c0..) — L0 runs ahead, usually
        // ready; hides the h2 recurrent-chain spin behind this GEMM.
        loadB(c0, 0);
        loadB(c0 + 1, 1);
        loadB(c0 + 2, 2);
        if (lane < nc) spin1(fL0 + c0 + lane, n + 1);               // h0(n) visible
#pragma unroll
        for (int i = 0; i < 5; ++i) if (i < nc) loadA(h0cur, c0 + i, i);
#pragma unroll
        for (int i = 0; i < 5; ++i) if (i < nc) {
          const h8 A = Ab[i];
#pragma unroll
          for (int nt = 0; nt < 8; ++nt)
            acc[nt] = __builtin_amdgcn_mfma_f32_16x16x32_f16(A, Bb[i % 3][nt], acc[nt], 0, 0, 0);
          if (i + 3 < nc) loadB(c0 + i + 3, i % 3);
        }

        // ---- phase B: h2(n-1) part (weights 32+c0..) — the recurrent chain
        loadB(32 + c0, 0);
        loadB(32 + c0 + 1, 1);
        loadB(32 + c0 + 2, 2);
        if (lane < nc) spin1(fL1 + c0 + lane, n);                   // h2(n-1) visible
#pragma unroll
        for (int i = 0; i < 5; ++i) if (i < nc) loadA(h2prev, c0 + i, i);
#pragma unroll
        for (int i = 0; i < 5; ++i) if (i < nc) {
          const h8 A = Ab[i];
#pragma unroll
          for (int nt = 0; nt < 8; ++nt)
            acc[nt] = __builtin_amdgcn_mfma_f32_16x16x32_f16(A, Bb[i % 3][nt], acc[nt], 0, 0, 0);
          if (i + 3 < nc) loadB(32 + c0 + i + 3, i % 3);
        }
        dump(acc);
      }
      // slot n&1 overwrites h2(n-2): L1 peers (step n-1 phase B) done iff fL1 >= n.
      pointwise_publish(h2q + (n & 1) * 65536, n, n);
    }
  }
}

// ---------------------------------------------------------------------------
__global__ void head_kernel(const _Float16* __restrict__ h2s, const float* __restrict__ Wh,
                            const float* __restrict__ bh, float* __restrict__ out)
{
  const int blk = blockIdx.x;            // 64*24
  const int b = blk / 24, j = blk % 24;
  const int lane = threadIdx.x;          // 64
  float sum = 0.f;
#pragma unroll
  for (int k0 = 0; k0 < 1024; k0 += 64) {
    const int hid = k0 + lane;
    const float hv = (float)h2s[((hid >> 5) * 4 + (b >> 4)) * 512 + (b & 15) * 32 + (hid & 31)];
    sum += hv * Wh[(long)j * 1024 + hid];
  }
#pragma unroll
  for (int off = 32; off > 0; off >>= 1)
    sum += __shfl_down(sum, off, 64);
  if (lane == 0) out[b * 24 + j] = sum + bh[j];
}

// ---------------------------------------------------------------------------
extern "C" void kernel_launch(void* const* d_in, const int* in_sizes, int n_in,
                              void* d_out, int out_size, void* d_ws, size_t ws_size,
                              hipStream_t stream)
{
  const float* x    = (const float*)d_in[0];
  const float* Wih0 = (const float*)d_in[1];
  const float* Whh0 = (const float*)d_in[2];
  const float* bih0 = (const float*)d_in[3];
  const float* bhh0 = (const float*)d_in[4];
  const float* Wih1 = (const float*)d_in[5];
  const float* Whh1 = (const float*)d_in[6];
  const float* bih1 = (const float*)d_in[7];
  const float* bhh1 = (const float*)d_in[8];
  const float* Whd  = (const float*)d_in[9];
  const float* bhd  = (const float*)d_in[10];

  char* ws = (char*)d_ws;
  _Float16* W0p     = (_Float16*)(ws + WS_W0P);
  _Float16* W1p     = (_Float16*)(ws + WS_W1P);
  _Float16* h0q     = (_Float16*)(ws + WS_H0Q);
  _Float16* h2q     = (_Float16*)(ws + WS_H2Q);
  unsigned* sync_ws = (unsigned*)(ws + WS_SYNC);
  float* out = (float*)d_out;

  const bool use_xpk = (ws_size >= WS_XPK_END);
  _Float16* xpk = use_xpk ? (_Float16*)(ws + WS_XPK) : nullptr;

  prep_kernel<<<dim3(2048), dim3(256), 0, stream>>>(
      x, Wih0, Whh0, Wih1, Whh1, W0p, W1p, xpk,
      (unsigned*)(ws + WS_H0Q), sync_ws);

  // static ~3.7 KB + dynamic 86,016 B LDS -> 1 WG/CU -> 256 WGs co-resident.
  if (use_xpk)
    lstm_kernel<true><<<dim3(256), dim3(512), 86016, stream>>>(
        x, xpk, bih0, bhh0, bih1, bhh1, W0p, W1p, h0q, h2q, sync_ws);
  else
    lstm_kernel<false><<<dim3(256), dim3(512), 86016, stream>>>(
        x, nullptr, bih0, bhh0, bih1, bhh1, W0p, W1p, h0q, h2q, sync_ws);

  head_kernel<<<dim3(64 * 24), dim3(64), 0, stream>>>(
      h2q + 65536, Whd, bhd, out);   // h2(511), slot 511&1 = 1
}

// Round 5
// 4550.517 us; speedup vs baseline: 2.3936x; 1.6504x over previous
//
#include <hip/hip_runtime.h>

// ============================================================================
// 2-layer LSTM (B=64,T=512,I=256,H=1024) + head. Persistent kernel, R10.
//
// R10 = R7 (best verified, 4564us) + conflict-free gbufT.
//
// R8/R9 post-mortem: chunk remap + modulo-indexed prefetch buffers under
// runtime predication demoted the pipeline out of registers (VGPR stuck at
// 128 while live set needed ~170) -> per-lane memory traffic -> FETCH 10x.
// Reverted wholesale.
//
// R10 change (only one): gbufT stride 24 -> 32 with per-row column rotation
//   rot(row) = ((row&3)<<3) | (((row>>2)&1)<<2),  phys_word = (w + rot) & 31
//  * dump (b128 writes): 8-lane phases hit 8 distinct 16B slots = all 32
//    banks once -> conflict-free (was 2-way at stride 24).
//  * reduce (b32 reads): per-wave row starts {0,8,16,24}+const -> every
//    bank exactly 2 lanes -> free (was 2-way@24 / 3-way@20).
//  * SQ_LDS_BANK_CONFLICT was pinned at 2.68e8 through R5-R7 because the
//    20/24 strides only traded dump-conflicts for reduce-conflicts.
//  * LDS: 131,072 B dynamic + ~3.7 KB static = 134.8 KB < 160 KB, 1 WG/CU.
//
// Workspace (44,834,816 B):
//   0         W0p  fp16 [32 cs][40 c][8 nt][512]   10,485,760
//   10485760  W1p  fp16 [32 cs][64 c][8 nt][512]   16,777,216
//   27262976  h0q  fp16 4 slots x [32 c][4 bg][512]   524,288
//   27787264  h2q  fp16 2 slots x same                262,144
//   28049408  sync uint[2048]: flag[(lay*4+bg)*32 + cs], 128B/group  8,192
//   28057600  xpk  fp16 [512 t][8 c][4 bg][512]    16,777,216
// ============================================================================

typedef _Float16 h8 __attribute__((ext_vector_type(8)));
typedef float    f4 __attribute__((ext_vector_type(4)));
typedef unsigned long long u64;

#define WS_W0P   0
#define WS_W1P   10485760
#define WS_H0Q   27262976
#define WS_H2Q   27787264
#define WS_SYNC  28049408
#define WS_XPK   28057600
#define WS_XPK_END 44834816ULL

static __device__ __forceinline__ float sigm(float v) { return 1.f / (1.f + __expf(-v)); }
static __device__ __forceinline__ float tanh_fast(float v) {
  const float e = __expf(2.f * v);
  return 1.f - 2.f / (e + 1.f);
}
static __device__ __forceinline__ h8 vload16(const _Float16* p) {
  return *(const volatile h8*)p;          // coherent (MALL) 16B load
}
static __device__ __forceinline__ void vstore16(_Float16* p, h8 v) {
  *(volatile h8*)p = v;                   // coherent (MALL) 16B store
}

// ---------------------------------------------------------------------------
__global__ void prep_kernel(const float* __restrict__ x,
                            const float* __restrict__ Wih0, const float* __restrict__ Whh0,
                            const float* __restrict__ Wih1, const float* __restrict__ Whh1,
                            _Float16* __restrict__ W0p, _Float16* __restrict__ W1p,
                            _Float16* __restrict__ xpk,
                            unsigned* __restrict__ hz, unsigned* __restrict__ sync_ws)
{
  const long tid0 = (long)blockIdx.x * blockDim.x + threadIdx.x;
  const long np   = (long)gridDim.x * blockDim.x;

  // W0p: e = ((cs*40 + c)*8 + nt)*512 + l15*32 + quad*8 + j
  for (long e = tid0; e < 5242880; e += np) {
    const int j = e & 7, quad = (e >> 3) & 3, l15 = (e >> 5) & 15, nt = (e >> 9) & 7;
    const int r = (int)(e >> 12);
    const int c = r % 40, cs = r / 40;
    const int col = nt * 16 + l15;
    const int row = (col >> 5) * 1024 + cs * 32 + (col & 31);
    const int k = c * 32 + quad * 8 + j;
    const float v = (k < 256) ? Wih0[(long)row * 256 + k] : Whh0[(long)row * 1024 + k - 256];
    W0p[e] = (_Float16)v;
  }
  // W1p: r = cs*64 + c
  for (long e = tid0; e < 8388608; e += np) {
    const int j = e & 7, quad = (e >> 3) & 3, l15 = (e >> 5) & 15, nt = (e >> 9) & 7;
    const int r = (int)(e >> 12);
    const int c = r & 63, cs = r >> 6;
    const int col = nt * 16 + l15;
    const int row = (col >> 5) * 1024 + cs * 32 + (col & 31);
    const int k = c * 32 + quad * 8 + j;
    const float v = (k < 1024) ? Wih1[(long)row * 1024 + k] : Whh1[(long)row * 1024 + k - 1024];
    W1p[e] = (_Float16)v;
  }
  // xpk: e = ((t*8 + c)*4 + bg)*512 + b16*32 + k32
  if (xpk) {
    for (long e = tid0; e < 8388608; e += np) {
      const int k32 = e & 31, b16 = (e >> 5) & 15, bg = (e >> 9) & 3;
      const int c = (e >> 11) & 7;
      const int t = (int)(e >> 14);
      const int b = bg * 16 + b16, k = c * 32 + k32;
      xpk[e] = (_Float16)x[(long)b * 131072 + (long)t * 256 + k];
    }
  }
  for (long e = tid0; e < 196608; e += np) hz[e] = 0u;   // h0q + h2q
  if (tid0 < 2048) sync_ws[tid0] = 0u;
}

// ---------------------------------------------------------------------------
// sync layout (uint idx): flag[(lay*4+bg)*32 + cs]. One 128-B line per
// (lay,bg) group. Flag value = n+1 once that WG's h(n) slice is MALL-visible.
// ---------------------------------------------------------------------------
template<bool XP>
__launch_bounds__(512, 1)
__global__ void lstm_kernel(const float* __restrict__ x, const _Float16* __restrict__ xpk,
                            const float* __restrict__ bih0, const float* __restrict__ bhh0,
                            const float* __restrict__ bih1, const float* __restrict__ bhh1,
                            const _Float16* __restrict__ W0p, const _Float16* __restrict__ W1p,
                            _Float16* __restrict__ h0q, _Float16* __restrict__ h2q,
                            unsigned* __restrict__ sy)
{
  extern __shared__ float gb[];                    // gbufT [8][128][32] = 131,072 B
  __shared__ float cst[512];                       // c-state, slot = tid (hh*16+b16)
  __shared__ float biasl[128];
  __shared__ _Float16 htmp[32 * 18];               // [hh][b16] pad 18

  const int tid = threadIdx.x, wg = blockIdx.x;
  const int xcd = wg & 7, jdec = wg >> 3;
  const int lay = jdec & 1, jj = jdec >> 1;
  const int bg = jj & 3, csl = jj >> 2;
  const int cs = xcd * 4 + csl;                    // col-slice 0..31 (XCD-local)
  const int lane = tid & 63, kg = tid >> 6;
  const int l15 = lane & 15, quad = lane >> 4;
  const int boff = l15 * 32 + quad * 8;            // B-frag offset in 1024-blk
  const int aoff = bg * 512 + l15 * 32 + quad * 8; // A-frag offset in 2048-blk

  const _Float16* Wp = lay ? (W1p + (long)cs * 262144) : (W0p + (long)cs * 163840);

  if (tid < 128) {
    const int row = (tid >> 5) * 1024 + cs * 32 + (tid & 31);
    biasl[tid] = lay ? (bih1[row] + bhh1[row]) : (bih0[row] + bhh0[row]);
  }
  cst[tid] = 0.f;
  __syncthreads();

  unsigned* const fL0  = sy + (bg * 32);           // layer-0 flags, this bg (1 line)
  unsigned* const fL1  = sy + ((4 + bg) * 32);     // layer-1 flags, this bg (1 line)
  unsigned* const fOwn = (lay ? fL1 : fL0) + cs;   // this WG's flag

  auto spin1 = [&](const unsigned* p, int tgt) {   // exits immediately if tgt<=0
    while ((int)__hip_atomic_load(p, __ATOMIC_RELAXED, __HIP_MEMORY_SCOPE_AGENT) < tgt)
      __builtin_amdgcn_s_sleep(2);
  };

  // conflict-free gbufT: phys word = (w + rot(row)) & 31,
  // rot(row) = ((row&3)<<3) | (((row>>2)&1)<<2)   (bijective per row)
  const int rotd = ((l15 & 3) << 3) | (((l15 >> 2) & 1) << 2);   // dump rot (row&3=l15&3)
  auto dump = [&](const f4* acc) {
#pragma unroll
    for (int nt = 0; nt < 8; ++nt)
      *(f4*)&gb[(kg * 128 + nt * 16 + l15) * 32 + ((quad * 4 + rotd) & 31)] = acc[nt];
  };

  // gate: slot-free flags (fL1), gtgt: required value; polled by wave-0 lanes
  auto pointwise_publish = [&](_Float16* wr, int n, int gtgt) {
    __syncthreads();                               // gbufT complete
    {
      const int b16 = tid & 15, hh = tid >> 4;
      const int rotr = ((hh & 3) << 3) | (((hh >> 2) & 1) << 2);  // (row>>2)&1 == (hh>>2)&1
      float gv[4];
#pragma unroll
      for (int gt = 0; gt < 4; ++gt) {
        float s = biasl[gt * 32 + hh];
#pragma unroll
        for (int k = 0; k < 8; ++k)
          s += gb[(k * 128 + gt * 32 + hh) * 32 + ((b16 + rotr) & 31)];
        gv[gt] = s;
      }
      const float si = sigm(gv[0]), sf = sigm(gv[1]);
      const float tg = tanh_fast(gv[2]), so = sigm(gv[3]);
      const float cn = sf * cst[tid] + si * tg;
      cst[tid] = cn;
      htmp[hh * 18 + b16] = (_Float16)(so * tanh_fast(cn));
    }
    __syncthreads();                               // htmp complete; waves 1-7 run ahead
    if (tid < 64) {                                // wave 0: gate + pack + publish + flag
      if (tid < 32) spin1(fL1 + tid, gtgt);        // slot-free (usually satisfied)
      const int b16 = tid & 15, q = tid >> 4;
      union { h8 v; _Float16 e[8]; } r;
#pragma unroll
      for (int i = 0; i < 8; ++i) r.e[i] = htmp[(q * 8 + i) * 18 + b16];
      vstore16(wr + (cs * 4 + bg) * 512 + b16 * 32 + q * 8, r.v);
      asm volatile("s_waitcnt vmcnt(0)" ::: "memory");   // wave-local drain
      if (tid == 0)
        __hip_atomic_store(fOwn, (unsigned)(n + 1),
                           __ATOMIC_RELAXED, __HIP_MEMORY_SCOPE_AGENT);
    }
  };

  if (lay == 0) {
    const int c0 = kg * 5;
    for (int n = 0; n < 512; ++n) {
      const _Float16* h0prev = h0q + ((n - 1) & 3) * 65536;
      const _Float16* xs = XP ? (xpk + (long)n * 16384) : nullptr;

      f4 acc[8] = {};
      h8 Ab[5]; h8 Bb[2][8];
      auto loadB = [&](int c, int sl) {
        const _Float16* bp = Wp + (long)c * 4096 + boff;
#pragma unroll
        for (int nt = 0; nt < 8; ++nt) Bb[sl][nt] = *(const h8*)(bp + nt * 512);
      };
      auto loadA = [&](int c, int idx) {
        if (c < 8) {
          if (XP) Ab[idx] = *(const h8*)(xs + c * 2048 + aoff);
          else {
            const float* q = x + (long)(bg * 16 + l15) * 131072 + (long)n * 256 + c * 32 + quad * 8;
            const f4 v0 = *(const f4*)q;
            const f4 v1 = *(const f4*)(q + 4);
            h8 t;
            t[0]=(_Float16)v0[0]; t[1]=(_Float16)v0[1]; t[2]=(_Float16)v0[2]; t[3]=(_Float16)v0[3];
            t[4]=(_Float16)v1[0]; t[5]=(_Float16)v1[1]; t[6]=(_Float16)v1[2]; t[7]=(_Float16)v1[3];
            Ab[idx] = t;
          }
        } else {
          Ab[idx] = vload16(h0prev + (c - 8) * 2048 + aoff);
        }
      };

      loadB(c0, 0);                                // static weights: pre-spin
#pragma unroll
      for (int i = 0; i < 5; ++i)
        if (c0 + i < 8) loadA(c0 + i, i);          // x-chunks: no dependency

      // per-wave, per-producer spin (lanes poll this wave's needed flags only)
      if (lane < 5) {
        const int c = c0 + lane;
        if (c >= 8) spin1(fL0 + (c - 8), n);       // h0(n-1) slice visible
      }

#pragma unroll
      for (int i = 0; i < 5; ++i)
        if (c0 + i >= 8) loadA(c0 + i, i);         // all h-frags in flight at once

#pragma unroll
      for (int i = 0; i < 5; ++i) {
        if (i + 1 < 5) loadB(c0 + i + 1, (i + 1) & 1);
        const h8 A = Ab[i];
#pragma unroll
        for (int nt = 0; nt < 8; ++nt)
          acc[nt] = __builtin_amdgcn_mfma_f32_16x16x32_f16(A, Bb[i & 1][nt], acc[nt], 0, 0, 0);
      }
      dump(acc);
      // slot n&3 overwrites h0(n-4): L1 consumers (step n-4) done iff fL1 >= n-3.
      pointwise_publish(h0q + (n & 3) * 65536, n, n - 3);
    }
  } else {
    const int c0 = kg * 4;
    for (int n = 0; n < 512; ++n) {
      const _Float16* h0cur  = h0q + (n & 3) * 65536;
      const _Float16* h2prev = h2q + ((n - 1) & 1) * 65536;

      f4 acc[8] = {};
      h8 Ab[4]; h8 Bb[2][8];
      auto loadB = [&](int c, int sl) {
        const _Float16* bp = Wp + (long)c * 4096 + boff;
#pragma unroll
        for (int nt = 0; nt < 8; ++nt) Bb[sl][nt] = *(const h8*)(bp + nt * 512);
      };
      auto loadA = [&](const _Float16* hb, int cloc, int idx) {
        Ab[idx] = vload16(hb + cloc * 2048 + aoff);
      };

      // ---- phase A FIRST: h0(n) part (weights c0..c0+3) — L0 runs ahead,
      // usually ready; hides the h2 recurrent-chain spin behind this GEMM.
      loadB(c0, 0);                                // pre-spin weight prefetch
      if (lane < 4) spin1(fL0 + c0 + lane, n + 1); // h0(n) slices visible
#pragma unroll
      for (int i = 0; i < 4; ++i) loadA(h0cur, c0 + i, i);
#pragma unroll
      for (int i = 0; i < 4; ++i) {
        if (i + 1 < 4) loadB(c0 + i + 1, (i + 1) & 1);
        const h8 A = Ab[i];
#pragma unroll
        for (int nt = 0; nt < 8; ++nt)
          acc[nt] = __builtin_amdgcn_mfma_f32_16x16x32_f16(A, Bb[i & 1][nt], acc[nt], 0, 0, 0);
      }

      // ---- phase B: h2(n-1) part (weights 32+c0..) — the recurrent chain
      loadB(32 + c0, 0);                           // pre-spin weight prefetch
      if (lane < 4) spin1(fL1 + c0 + lane, n);     // h2(n-1) slices visible
#pragma unroll
      for (int i = 0; i < 4; ++i) loadA(h2prev, c0 + i, i);
#pragma unroll
      for (int i = 0; i < 4; ++i) {
        if (i + 1 < 4) loadB(32 + c0 + i + 1, (i + 1) & 1);
        const h8 A = Ab[i];
#pragma unroll
        for (int nt = 0; nt < 8; ++nt)
          acc[nt] = __builtin_amdgcn_mfma_f32_16x16x32_f16(A, Bb[i & 1][nt], acc[nt], 0, 0, 0);
      }
      dump(acc);
      // slot n&1 overwrites h2(n-2): L1 peers (step n-1 phase B) done iff fL1 >= n.
      pointwise_publish(h2q + (n & 1) * 65536, n, n);
    }
  }
}

// ---------------------------------------------------------------------------
__global__ void head_kernel(const _Float16* __restrict__ h2s, const float* __restrict__ Wh,
                            const float* __restrict__ bh, float* __restrict__ out)
{
  const int blk = blockIdx.x;            // 64*24
  const int b = blk / 24, j = blk % 24;
  const int lane = threadIdx.x;          // 64
  float sum = 0.f;
#pragma unroll
  for (int k0 = 0; k0 < 1024; k0 += 64) {
    const int hid = k0 + lane;
    const float hv = (float)h2s[((hid >> 5) * 4 + (b >> 4)) * 512 + (b & 15) * 32 + (hid & 31)];
    sum += hv * Wh[(long)j * 1024 + hid];
  }
#pragma unroll
  for (int off = 32; off > 0; off >>= 1)
    sum += __shfl_down(sum, off, 64);
  if (lane == 0) out[b * 24 + j] = sum + bh[j];
}

// ---------------------------------------------------------------------------
extern "C" void kernel_launch(void* const* d_in, const int* in_sizes, int n_in,
                              void* d_out, int out_size, void* d_ws, size_t ws_size,
                              hipStream_t stream)
{
  const float* x    = (const float*)d_in[0];
  const float* Wih0 = (const float*)d_in[1];
  const float* Whh0 = (const float*)d_in[2];
  const float* bih0 = (const float*)d_in[3];
  const float* bhh0 = (const float*)d_in[4];
  const float* Wih1 = (const float*)d_in[5];
  const float* Whh1 = (const float*)d_in[6];
  const float* bih1 = (const float*)d_in[7];
  const float* bhh1 = (const float*)d_in[8];
  const float* Whd  = (const float*)d_in[9];
  const float* bhd  = (const float*)d_in[10];

  char* ws = (char*)d_ws;
  _Float16* W0p     = (_Float16*)(ws + WS_W0P);
  _Float16* W1p     = (_Float16*)(ws + WS_W1P);
  _Float16* h0q     = (_Float16*)(ws + WS_H0Q);
  _Float16* h2q     = (_Float16*)(ws + WS_H2Q);
  unsigned* sync_ws = (unsigned*)(ws + WS_SYNC);
  float* out = (float*)d_out;

  const bool use_xpk = (ws_size >= WS_XPK_END);
  _Float16* xpk = use_xpk ? (_Float16*)(ws + WS_XPK) : nullptr;

  prep_kernel<<<dim3(2048), dim3(256), 0, stream>>>(
      x, Wih0, Whh0, Wih1, Whh1, W0p, W1p, xpk,
      (unsigned*)(ws + WS_H0Q), sync_ws);

  // static ~3.7 KB + dynamic 131,072 B LDS -> 1 WG/CU -> 256 WGs co-resident.
  if (use_xpk)
    lstm_kernel<true><<<dim3(256), dim3(512), 131072, stream>>>(
        x, xpk, bih0, bhh0, bih1, bhh1, W0p, W1p, h0q, h2q, sync_ws);
  else
    lstm_kernel<false><<<dim3(256), dim3(512), 131072, stream>>>(
        x, nullptr, bih0, bhh0, bih1, bhh1, W0p, W1p, h0q, h2q, sync_ws);

  head_kernel<<<dim3(64 * 24), dim3(64), 0, stream>>>(
      h2q + 65536, Whd, bhd, out);   // h2(511), slot 511&1 = 1
}